// Round 5
// baseline (866.488 us; speedup 1.0000x reference)
//
#include <hip/hip_runtime.h>
#include <stdint.h>

#define TT 50
#define NSTEP 49
#define NBATCH 4096
#define SS 100
#define HH 256
#define K1 128
#define SA_LD 136   // sA leading dim (shorts): stride 272B -> 2-way banks max
#define XB_LD 260   // xb leading dim (floats): stride 1040B -> 2-way banks max

typedef short bf16x8 __attribute__((ext_vector_type(8)));
typedef float f32x4 __attribute__((ext_vector_type(4)));
typedef float f32x2 __attribute__((ext_vector_type(2)));

#define MFMA(a, b, c) __builtin_amdgcn_mfma_f32_16x16x32_bf16((a), (b), (c), 0, 0, 0)

// Fragment-linear weight layouts: [t][nt][ks][lane][8 bf16], 16B per lane.
#define W1G_OFF(t, nt, ks) ((((size_t)(t) * 16 + (nt)) * 4 + (ks)) * 512)
#define W2G_OFF(t, nt, ks) ((((size_t)(t) * 16 + (nt)) * 8 + (ks)) * 512)
#define WOG_OFF(t, nt, ks) ((((size_t)(t) * 8 + (nt)) * 8 + (ks)) * 512)
#define N_W1G W1G_OFF(TT, 0, 0)
#define N_W2G W2G_OFF(TT, 0, 0)
#define N_WOG WOG_OFF(TT, 0, 0)

__device__ __forceinline__ short f2b(float f) {
  union { float f; uint32_t u; } v;
  v.f = f;
  return (short)((v.u + 0x7FFFu + ((v.u >> 16) & 1u)) >> 16);
}

__global__ void zero_out(float* out) {
  if (threadIdx.x == 0 && blockIdx.x == 0) out[0] = 0.f;
}

// Coalesced prep: stage a 16-row chunk in LDS (contiguous global reads),
// emit fragment-linear bf16 (contiguous global writes). b1 is baked into
// W1 fragments at k==100 (the main kernel feeds a constant-1 input there).
__global__ __launch_bounds__(256) void prep(
    const float* __restrict__ W1, const float* __restrict__ b1,
    const float* __restrict__ W2, const float* __restrict__ Wo,
    short* __restrict__ W1g, short* __restrict__ W2g, short* __restrict__ Wog,
    float* __restrict__ out) {
  __shared__ float tile[16 * 264];
  const int tid = threadIdx.x;
  const int wg = blockIdx.x;
  if (wg == 0 && tid == 0) out[0] = 0.f;
  if (wg < 800) {                     // W1: wg = t*16 + nt
    const int t = wg >> 4, nt = wg & 15;
    const float* src = W1 + ((size_t)t * HH + nt * 16) * SS;
    const float* bsrc = b1 + t * HH + nt * 16;
    for (int i = tid; i < 16 * K1; i += 256) {
      int m = i >> 7, k = i & 127;
      float v = (k < SS) ? src[m * SS + k] : (k == SS ? bsrc[m] : 0.f);
      tile[m * 264 + k] = v;
    }
    __syncthreads();
    {
      int ks = tid >> 6, lane = tid & 63;
      int qq = lane >> 4, cc = lane & 15;
      bf16x8 v;
#pragma unroll
      for (int j = 0; j < 8; ++j) v[j] = f2b(tile[cc * 264 + ks * 32 + qq * 8 + j]);
      *(bf16x8*)&W1g[W1G_OFF(t, nt, ks) + lane * 8] = v;
    }
  } else if (wg < 1600) {             // W2
    const int h = wg - 800;
    const int t = h >> 4, nt = h & 15;
    const float* src = W2 + ((size_t)t * HH + nt * 16) * HH;
    for (int i = tid; i < 16 * HH; i += 256) {
      int m = i >> 8, k = i & 255;
      tile[m * 264 + k] = src[m * HH + k];
    }
    __syncthreads();
    for (int gi = tid; gi < 512; gi += 256) {
      int ks = gi >> 6, lane = gi & 63;
      int qq = lane >> 4, cc = lane & 15;
      bf16x8 v;
#pragma unroll
      for (int j = 0; j < 8; ++j) v[j] = f2b(tile[cc * 264 + ks * 32 + qq * 8 + j]);
      *(bf16x8*)&W2g[W2G_OFF(t, nt, ks) + lane * 8] = v;
    }
  } else {                            // Wo (N padded 100->128)
    const int h = wg - 1600;
    const int t = h >> 3, nt = h & 7;
    for (int i = tid; i < 16 * HH; i += 256) {
      int m = i >> 8, k = i & 255;
      int n = nt * 16 + m;
      tile[m * 264 + k] = (n < SS) ? Wo[((size_t)t * SS + n) * HH + k] : 0.f;
    }
    __syncthreads();
    for (int gi = tid; gi < 512; gi += 256) {
      int ks = gi >> 6, lane = gi & 63;
      int qq = lane >> 4, cc = lane & 15;
      bf16x8 v;
#pragma unroll
      for (int j = 0; j < 8; ++j) v[j] = f2b(tile[cc * 264 + ks * 32 + qq * 8 + j]);
      *(bf16x8*)&Wog[WOG_OFF(t, nt, ks) + lane * 8] = v;
    }
  }
}

// One wave per block; each wave owns 16 batch rows for all 49 steps.
// No __syncthreads in the step loop: all cross-lane traffic is in-wave
// (shfl + wave-private LDS, ordered by lgkmcnt). ks-outer MFMA loops give
// 16/8 independent accumulator chains (no dependent-MFMA stalls); B-frags
// double-buffered across ks (1 wave/SIMD -> ~512 VGPR budget).
template <int MODE>
__global__ __launch_bounds__(64, 1) void run_kernel(
    const float* __restrict__ s0, const float* __restrict__ prices,
    const float* __restrict__ b1v, const float* __restrict__ g1v, const float* __restrict__ be1v,
    const float* __restrict__ b2v, const float* __restrict__ g2v, const float* __restrict__ be2v,
    const float* __restrict__ bov,
    const float* __restrict__ W1f, const float* __restrict__ W2f, const float* __restrict__ Wof,
    const short* __restrict__ W1g, const short* __restrict__ W2g, const short* __restrict__ Wog,
    float* __restrict__ out) {
  __shared__ short sA[16 * SA_LD];    // s in A-layout bf16; k==100 is the bias-one lane
  __shared__ float xb0[16 * XB_LD];   // pre-norm h1 (f32)
  __shared__ float xb1b[16 * XB_LD];  // pre-norm h2 (f32)
  __shared__ float st0[32];           // (mu, rstd) per row
  __shared__ float st1[32];

  const int lane = threadIdx.x;
  const int q = lane >> 4, c16 = lane & 15;
  const int b0 = blockIdx.x * 16;

  // init sA: rows m=0..15, k<100 = s0, k==100 = 1.0 (bias lane), else 0
  for (int i = lane; i < 16 * K1; i += 64) {
    int m = i >> 7, k = i & 127;
    float v = (k < SS) ? s0[(size_t)(b0 + m) * SS + k] : (k == SS ? 1.f : 0.f);
    sA[m * SA_LD + k] = f2b(v);
  }
  // per-lane f32 carry: rows q*4+r, cols nt*16+c16 (nt<8)
  float s_reg[8][4];
  float pr[8][4];
#pragma unroll
  for (int nt = 0; nt < 8; ++nt)
#pragma unroll
    for (int r = 0; r < 4; ++r) {
      int col = nt * 16 + c16;
      bool v = col < SS;
      s_reg[nt][r] = v ? s0[(size_t)(b0 + q * 4 + r) * SS + col] : 0.f;
      pr[nt][r] = v ? prices[((size_t)(b0 + q * 4 + r) * TT) * SS + col] : 0.f;
    }
  float costreg = 0.f;

  auto loadB1 = [&](int tt, int nt, int ks) -> bf16x8 {
    if (MODE == 0) return *(const bf16x8*)&W1g[W1G_OFF(tt, nt, ks) + lane * 8];
    int n = nt * 16 + c16, kb = ks * 32 + q * 8;
    bf16x8 v;
#pragma unroll
    for (int j = 0; j < 8; ++j) {
      int k = kb + j;
      v[j] = (k < SS) ? f2b(W1f[((size_t)tt * HH + n) * SS + k])
                      : (k == SS ? f2b(b1v[tt * HH + n]) : (short)0);
    }
    return v;
  };
  auto loadB2 = [&](int tt, int nt, int ks) -> bf16x8 {
    if (MODE == 0) return *(const bf16x8*)&W2g[W2G_OFF(tt, nt, ks) + lane * 8];
    int n = nt * 16 + c16, kb = ks * 32 + q * 8;
    bf16x8 v;
#pragma unroll
    for (int j = 0; j < 8; ++j) v[j] = f2b(W2f[((size_t)tt * HH + n) * HH + kb + j]);
    return v;
  };
  auto loadB3 = [&](int tt, int nt, int ks) -> bf16x8 {
    if (MODE == 0) return *(const bf16x8*)&Wog[WOG_OFF(tt, nt, ks) + lane * 8];
    int n = nt * 16 + c16, kb = ks * 32 + q * 8;
    bf16x8 v;
    if (n < SS) {
#pragma unroll
      for (int j = 0; j < 8; ++j) v[j] = f2b(Wof[((size_t)tt * SS + n) * HH + kb + j]);
    } else {
      bf16x8 z = {0, 0, 0, 0, 0, 0, 0, 0};
      v = z;
    }
    return v;
  };

#pragma unroll 1
  for (int t = 0; t < NSTEP; ++t) {
    // ===== GEMM1: h1[16x256] = [s,1] @ [W1|b1]^T  (bias via k=100 lane) =====
    bf16x8 a1[4];
#pragma unroll
    for (int ks = 0; ks < 4; ++ks)
      a1[ks] = *(const bf16x8*)&sA[c16 * SA_LD + ks * 32 + q * 8];
    f32x4 acc1[16];
#pragma unroll
    for (int nt = 0; nt < 16; ++nt) acc1[nt] = (f32x4){0.f, 0.f, 0.f, 0.f};
    {
      bf16x8 bf[2][16];
#pragma unroll
      for (int nt = 0; nt < 16; ++nt) bf[0][nt] = loadB1(t, nt, 0);
#pragma unroll
      for (int ks = 0; ks < 4; ++ks) {
        if (ks < 3) {
#pragma unroll
          for (int nt = 0; nt < 16; ++nt) bf[(ks + 1) & 1][nt] = loadB1(t, nt, ks + 1);
        }
#pragma unroll
        for (int nt = 0; nt < 16; ++nt) acc1[nt] = MFMA(a1[ks], bf[ks & 1][nt], acc1[nt]);
      }
    }
    // LN1 stats (in-wave) + spill pre-norm h1 to LDS
    {
      float p1[4] = {0.f, 0.f, 0.f, 0.f}, p2[4] = {0.f, 0.f, 0.f, 0.f};
#pragma unroll
      for (int nt = 0; nt < 16; ++nt)
#pragma unroll
        for (int r = 0; r < 4; ++r) {
          float v = acc1[nt][r];
          p1[r] += v;
          p2[r] += v * v;
          xb0[(q * 4 + r) * XB_LD + nt * 16 + c16] = v;
        }
#pragma unroll
      for (int m = 1; m <= 8; m <<= 1)
#pragma unroll
        for (int r = 0; r < 4; ++r) {
          p1[r] += __shfl_xor(p1[r], m);
          p2[r] += __shfl_xor(p2[r], m);
        }
      if (c16 == 0) {
#pragma unroll
        for (int r = 0; r < 4; ++r) {
          float mean = p1[r] * (1.f / HH);
          float var = fmaxf(p2[r] * (1.f / HH) - mean * mean, 0.f);
          f32x2 s2;
          s2[0] = mean;
          s2[1] = rsqrtf(var + 1e-5f);
          *(f32x2*)&st0[(q * 4 + r) * 2] = s2;
        }
      }
    }
    // ===== GEMM2 A-construct: relu((h1-mu)*r*g1+be1), packed bf16 =====
    bf16x8 af[8];
    {
      float mu = st0[c16 * 2], rs = st0[c16 * 2 + 1];
#pragma unroll
      for (int ks = 0; ks < 8; ++ks) {
        const float* gp = g1v + t * HH + ks * 32 + q * 8;
        const float* bp = be1v + t * HH + ks * 32 + q * 8;
        f32x4 ga = *(const f32x4*)gp, gb = *(const f32x4*)(gp + 4);
        f32x4 ba = *(const f32x4*)bp, bb = *(const f32x4*)(bp + 4);
        f32x4 h0 = *(const f32x4*)&xb0[c16 * XB_LD + ks * 32 + q * 8];
        f32x4 h1 = *(const f32x4*)&xb0[c16 * XB_LD + ks * 32 + q * 8 + 4];
        bf16x8 v;
#pragma unroll
        for (int j = 0; j < 4; ++j) {
          float x0 = fmaxf((h0[j] - mu) * (rs * ga[j]) + ba[j], 0.f);
          float x1 = fmaxf((h1[j] - mu) * (rs * gb[j]) + bb[j], 0.f);
          v[j] = f2b(x0);
          v[4 + j] = f2b(x1);
        }
        af[ks] = v;
      }
    }
    // ===== GEMM2: h2[16x256] = x1 @ W2^T + b2 =====
    f32x4 acc2[16];
#pragma unroll
    for (int nt = 0; nt < 16; ++nt) acc2[nt] = (f32x4){0.f, 0.f, 0.f, 0.f};
    {
      bf16x8 bf[2][16];
#pragma unroll
      for (int nt = 0; nt < 16; ++nt) bf[0][nt] = loadB2(t, nt, 0);
#pragma unroll
      for (int ks = 0; ks < 8; ++ks) {
        if (ks < 7) {
#pragma unroll
          for (int nt = 0; nt < 16; ++nt) bf[(ks + 1) & 1][nt] = loadB2(t, nt, ks + 1);
        }
#pragma unroll
        for (int nt = 0; nt < 16; ++nt) acc2[nt] = MFMA(af[ks], bf[ks & 1][nt], acc2[nt]);
      }
    }
    // b2 bias + LN2 stats + spill pre-norm h2
    {
      float p1[4] = {0.f, 0.f, 0.f, 0.f}, p2[4] = {0.f, 0.f, 0.f, 0.f};
#pragma unroll
      for (int nt = 0; nt < 16; ++nt) {
        float bb = b2v[t * HH + nt * 16 + c16];
#pragma unroll
        for (int r = 0; r < 4; ++r) {
          float v = acc2[nt][r] + bb;
          p1[r] += v;
          p2[r] += v * v;
          xb1b[(q * 4 + r) * XB_LD + nt * 16 + c16] = v;
        }
      }
#pragma unroll
      for (int m = 1; m <= 8; m <<= 1)
#pragma unroll
        for (int r = 0; r < 4; ++r) {
          p1[r] += __shfl_xor(p1[r], m);
          p2[r] += __shfl_xor(p2[r], m);
        }
      if (c16 == 0) {
#pragma unroll
        for (int r = 0; r < 4; ++r) {
          float mean = p1[r] * (1.f / HH);
          float var = fmaxf(p2[r] * (1.f / HH) - mean * mean, 0.f);
          f32x2 s2;
          s2[0] = mean;
          s2[1] = rsqrtf(var + 1e-5f);
          *(f32x2*)&st1[(q * 4 + r) * 2] = s2;
        }
      }
    }
    // ===== GEMM3 A-construct =====
    {
      float mu = st1[c16 * 2], rs = st1[c16 * 2 + 1];
#pragma unroll
      for (int ks = 0; ks < 8; ++ks) {
        const float* gp = g2v + t * HH + ks * 32 + q * 8;
        const float* bp = be2v + t * HH + ks * 32 + q * 8;
        f32x4 ga = *(const f32x4*)gp, gb = *(const f32x4*)(gp + 4);
        f32x4 ba = *(const f32x4*)bp, bb = *(const f32x4*)(bp + 4);
        f32x4 h0 = *(const f32x4*)&xb1b[c16 * XB_LD + ks * 32 + q * 8];
        f32x4 h1 = *(const f32x4*)&xb1b[c16 * XB_LD + ks * 32 + q * 8 + 4];
        bf16x8 v;
#pragma unroll
        for (int j = 0; j < 4; ++j) {
          float x0 = fmaxf((h0[j] - mu) * (rs * ga[j]) + ba[j], 0.f);
          float x1 = fmaxf((h1[j] - mu) * (rs * gb[j]) + bb[j], 0.f);
          v[j] = f2b(x0);
          v[4 + j] = f2b(x1);
        }
        af[ks] = v;
      }
    }
    // ===== GEMM3: o[16x128] = x2 @ Wo^T =====
    f32x4 acc3[8];
#pragma unroll
    for (int nt = 0; nt < 8; ++nt) acc3[nt] = (f32x4){0.f, 0.f, 0.f, 0.f};
    {
      bf16x8 bf[2][8];
#pragma unroll
      for (int nt = 0; nt < 8; ++nt) bf[0][nt] = loadB3(t, nt, 0);
#pragma unroll
      for (int ks = 0; ks < 8; ++ks) {
        if (ks < 7) {
#pragma unroll
          for (int nt = 0; nt < 8; ++nt) bf[(ks + 1) & 1][nt] = loadB3(t, nt, ks + 1);
        }
#pragma unroll
        for (int nt = 0; nt < 8; ++nt) acc3[nt] = MFMA(af[ks], bf[ks & 1][nt], acc3[nt]);
      }
    }
    // ===== epilogue: a=min(o+bo,s); cost += p*a + 0.01*(p*a)^2; s -= a =====
#pragma unroll
    for (int nt = 0; nt < 8; ++nt) {
      int col = nt * 16 + c16;
      if (col < SS) {
        float bb = bov[t * SS + col];
#pragma unroll
        for (int r = 0; r < 4; ++r) {
          float o = acc3[nt][r] + bb;
          float a = fminf(o, s_reg[nt][r]);
          float pa = pr[nt][r] * a;
          costreg += pa + 0.01f * pa * pa;
          float sn = s_reg[nt][r] - a;
          s_reg[nt][r] = sn;
          sA[(q * 4 + r) * SA_LD + col] = f2b(sn);
        }
      }
    }
    // prices for step t+1 (t=48 loads p_T for the terminal term)
#pragma unroll
    for (int nt = 0; nt < 8; ++nt)
#pragma unroll
      for (int r = 0; r < 4; ++r) {
        int col = nt * 16 + c16;
        if (col < SS)
          pr[nt][r] = prices[((size_t)(b0 + q * 4 + r) * TT + t + 1) * SS + col];
      }
  }

  // terminal: cost += p_T*s + 0.01*(p_T*s)^2
#pragma unroll
  for (int nt = 0; nt < 8; ++nt)
#pragma unroll
    for (int r = 0; r < 4; ++r) {
      float pa = pr[nt][r] * s_reg[nt][r];
      costreg += pa + 0.01f * pa * pa;
    }
#pragma unroll
  for (int m = 1; m < 64; m <<= 1) costreg += __shfl_xor(costreg, m);
  if (lane == 0) atomicAdd(out, costreg * (1.f / NBATCH));
}

extern "C" void kernel_launch(void* const* d_in, const int* in_sizes, int n_in,
                              void* d_out, int out_size, void* d_ws, size_t ws_size,
                              hipStream_t stream) {
  const float* s0 = (const float*)d_in[0];
  const float* prices = (const float*)d_in[1];
  const float* W1 = (const float*)d_in[2];
  const float* b1 = (const float*)d_in[3];
  const float* g1 = (const float*)d_in[4];
  const float* be1 = (const float*)d_in[5];
  const float* W2 = (const float*)d_in[6];
  const float* b2 = (const float*)d_in[7];
  const float* g2 = (const float*)d_in[8];
  const float* be2 = (const float*)d_in[9];
  const float* Wo = (const float*)d_in[10];
  const float* bo = (const float*)d_in[11];
  float* out = (float*)d_out;

  const size_t need = (N_W1G + N_W2G + N_WOG) * sizeof(short);

  if (ws_size >= need) {
    short* W1g = (short*)d_ws;
    short* W2g = W1g + N_W1G;
    short* Wog = W2g + N_W2G;
    prep<<<dim3(2000), dim3(256), 0, stream>>>(W1, b1, W2, Wo, W1g, W2g, Wog, out);
    run_kernel<0><<<dim3(256), dim3(64), 0, stream>>>(
        s0, prices, b1, g1, be1, b2, g2, be2, bo,
        W1, W2, Wo, W1g, W2g, Wog, out);
  } else {
    zero_out<<<dim3(1), dim3(64), 0, stream>>>(out);
    run_kernel<1><<<dim3(256), dim3(64), 0, stream>>>(
        s0, prices, b1, g1, be1, b2, g2, be2, bo,
        W1, W2, Wo, (const short*)nullptr, (const short*)nullptr, (const short*)nullptr, out);
  }
}

// Round 6
// 403.852 us; speedup vs baseline: 2.1456x; 2.1456x over previous
//
#include <hip/hip_runtime.h>
#include <stdint.h>

#define TT 50
#define NSTEP 49
#define NBATCH 4096
#define SS 100
#define HH 256
#define K1 128      // padded K for GEMM1 (S=100 -> 128)
#define NO 128      // padded N for GEMM3 (C=100 -> 128)
#define MROWS 16
#define NBLK 256
#define NTHR 512    // 8 waves

typedef short bf16x8 __attribute__((ext_vector_type(8)));
typedef float f32x4 __attribute__((ext_vector_type(4)));

#define MFMA(a, b, c) __builtin_amdgcn_mfma_f32_16x16x32_bf16((a), (b), (c), 0, 0, 0)

// Fragment-linear weight layouts: [t][nt][ks][lane][8 bf16], 16B per lane.
#define W1G_OFF(t, nt, ks) ((((size_t)(t) * 16 + (nt)) * 4 + (ks)) * 512)
#define W2G_OFF(t, nt, ks) ((((size_t)(t) * 16 + (nt)) * 8 + (ks)) * 512)
#define WOG_OFF(t, nt, ks) ((((size_t)(t) * 8 + (nt)) * 8 + (ks)) * 512)
#define N_W1G W1G_OFF(TT, 0, 0)
#define N_W2G W2G_OFF(TT, 0, 0)
#define N_WOG WOG_OFF(TT, 0, 0)

// LDS-only barrier: waits ds ops but does NOT drain vmcnt, so pinned
// register prefetches of weights/prices stay in flight across the sync.
__device__ __forceinline__ void bar_lds() {
  __asm__ volatile("s_waitcnt lgkmcnt(0)\n\ts_barrier" ::: "memory");
}
// Pin all previously-issued loads: nothing may be scheduled across this.
__device__ __forceinline__ void pin_loads() { __builtin_amdgcn_sched_barrier(0); }

__device__ __forceinline__ short f2b(float f) {
  union { float f; uint32_t u; } v;
  v.f = f;
  return (short)((v.u + 0x7FFFu + ((v.u >> 16) & 1u)) >> 16);
}

__device__ __forceinline__ bf16x8 cvt8(const float* __restrict__ p) {
  bf16x8 r;
#pragma unroll
  for (int j = 0; j < 8; ++j) r[j] = f2b(p[j]);
  return r;
}

__device__ __forceinline__ bf16x8 ldpad(const float* __restrict__ rowp, int k, int kmax) {
  bf16x8 r;
#pragma unroll
  for (int j = 0; j < 8; ++j) {
    int kk = k + j;
    r[j] = (kk < kmax) ? f2b(rowp[kk]) : (short)0;
  }
  return r;
}

__global__ void zero_out(float* out) {
  if (threadIdx.x == 0 && blockIdx.x == 0) out[0] = 0.f;
}

// Coalesced prep: stage a 16-row chunk in LDS (contiguous global reads),
// emit fragment-linear bf16 (contiguous global writes). b1 baked at k==100
// is harmless for the main kernel (its A operand is 0 there; b1 added in LN).
__global__ __launch_bounds__(256) void prep(
    const float* __restrict__ W1, const float* __restrict__ b1,
    const float* __restrict__ W2, const float* __restrict__ Wo,
    short* __restrict__ W1g, short* __restrict__ W2g, short* __restrict__ Wog,
    float* __restrict__ out) {
  __shared__ float tile[16 * 264];
  const int tid = threadIdx.x;
  const int wg = blockIdx.x;
  if (wg == 0 && tid == 0) out[0] = 0.f;
  if (wg < 800) {                     // W1: wg = t*16 + nt
    const int t = wg >> 4, nt = wg & 15;
    const float* src = W1 + ((size_t)t * HH + nt * 16) * SS;
    const float* bsrc = b1 + t * HH + nt * 16;
    for (int i = tid; i < 16 * K1; i += 256) {
      int m = i >> 7, k = i & 127;
      float v = (k < SS) ? src[m * SS + k] : (k == SS ? bsrc[m] : 0.f);
      tile[m * 264 + k] = v;
    }
    __syncthreads();
    {
      int ks = tid >> 6, lane = tid & 63;
      int qq = lane >> 4, cc = lane & 15;
      bf16x8 v;
#pragma unroll
      for (int j = 0; j < 8; ++j) v[j] = f2b(tile[cc * 264 + ks * 32 + qq * 8 + j]);
      *(bf16x8*)&W1g[W1G_OFF(t, nt, ks) + lane * 8] = v;
    }
  } else if (wg < 1600) {             // W2
    const int h = wg - 800;
    const int t = h >> 4, nt = h & 15;
    const float* src = W2 + ((size_t)t * HH + nt * 16) * HH;
    for (int i = tid; i < 16 * HH; i += 256) {
      int m = i >> 8, k = i & 255;
      tile[m * 264 + k] = src[m * HH + k];
    }
    __syncthreads();
    for (int gi = tid; gi < 512; gi += 256) {
      int ks = gi >> 6, lane = gi & 63;
      int qq = lane >> 4, cc = lane & 15;
      bf16x8 v;
#pragma unroll
      for (int j = 0; j < 8; ++j) v[j] = f2b(tile[cc * 264 + ks * 32 + qq * 8 + j]);
      *(bf16x8*)&W2g[W2G_OFF(t, nt, ks) + lane * 8] = v;
    }
  } else {                            // Wo (N padded 100->128)
    const int h = wg - 1600;
    const int t = h >> 3, nt = h & 7;
    for (int i = tid; i < 16 * HH; i += 256) {
      int m = i >> 8, k = i & 255;
      int n = nt * 16 + m;
      tile[m * 264 + k] = (n < SS) ? Wo[((size_t)t * SS + n) * HH + k] : 0.f;
    }
    __syncthreads();
    for (int gi = tid; gi < 512; gi += 256) {
      int ks = gi >> 6, lane = gi & 63;
      int qq = lane >> 4, cc = lane & 15;
      bf16x8 v;
#pragma unroll
      for (int j = 0; j < 8; ++j) v[j] = f2b(tile[cc * 264 + ks * 32 + qq * 8 + j]);
      *(bf16x8*)&Wog[WOG_OFF(t, nt, ks) + lane * 8] = v;
    }
  }
}

// Persistent kernel: 256 blocks x 8 waves; block owns 16 batch rows.
// Register prefetch of next phase's weights, pinned with sched_barrier(0)
// so the compiler cannot sink the loads; bar_lds keeps them in flight.
template <int MODE>
__global__ __launch_bounds__(NTHR, 2) void run_kernel(
    const float* __restrict__ s0, const float* __restrict__ prices,
    const float* __restrict__ b1, const float* __restrict__ g1, const float* __restrict__ be1,
    const float* __restrict__ b2, const float* __restrict__ g2, const float* __restrict__ be2,
    const float* __restrict__ bo,
    const float* __restrict__ W1f, const float* __restrict__ W2f, const float* __restrict__ Wof,
    const short* __restrict__ W1g, const short* __restrict__ W2g, const short* __restrict__ Wog,
    float* __restrict__ out) {
  __shared__ short sbuf[MROWS][K1 + 8];
  __shared__ short xb1[MROWS][HH + 8];
  __shared__ short xb2[MROWS][HH + 8];
  __shared__ float lnred[MROWS][17];
  __shared__ float wsum[8];

  const int tid = threadIdx.x;
  const int w = tid >> 6;
  const int lane = tid & 63;
  const int q = lane >> 4;
  const int c16 = lane & 15;
  const int b0 = blockIdx.x * MROWS;

  const int n0 = w * 32 + c16;   // GEMM1/2 n-tile cols (tiles 2w, 2w+1)
  const int n1 = n0 + 16;
  const int col = w * 16 + c16;  // GEMM3 / epilogue col (tile w)
  const bool cvalid = col < SS;

  for (int j = tid; j < MROWS * (K1 + 8); j += NTHR) ((short*)sbuf)[j] = 0;
  __syncthreads();

  float s_reg[4];
#pragma unroll
  for (int r = 0; r < 4; ++r) {
    int row = q * 4 + r;
    s_reg[r] = cvalid ? s0[(size_t)(b0 + row) * SS + col] : 0.f;
    if (cvalid) sbuf[row][col] = f2b(s_reg[r]);
  }
  __syncthreads();

  bf16x8 w1f[8];
  auto loadW1 = [&](int t) {
#pragma unroll
    for (int ks = 0; ks < 4; ++ks) {
      if (MODE == 0) {
        w1f[2 * ks + 0] = *(const bf16x8*)&W1g[W1G_OFF(t, 2 * w, ks) + lane * 8];
        w1f[2 * ks + 1] = *(const bf16x8*)&W1g[W1G_OFF(t, 2 * w + 1, ks) + lane * 8];
      } else {
        const int k = ks * 32 + q * 8;
        w1f[2 * ks + 0] = ldpad(W1f + ((size_t)t * HH + n0) * SS, k, SS);
        w1f[2 * ks + 1] = ldpad(W1f + ((size_t)t * HH + n1) * SS, k, SS);
      }
    }
  };
  float pr[4];
  auto loadP = [&](int t) {
#pragma unroll
    for (int r = 0; r < 4; ++r) {
      int row = q * 4 + r;
      pr[r] = cvalid ? prices[((size_t)(b0 + row) * TT + t) * SS + col] : 0.f;
    }
  };

  auto ln_epi = [&](f32x4& a0, f32x4& a1, float bv0, float bv1, float gv0, float gv1,
                    float ev0, float ev1, short (*dst)[HH + 8]) {
    float p1[4], p2[4];
#pragma unroll
    for (int r = 0; r < 4; ++r) {
      float v0 = a0[r] + bv0;
      float v1 = a1[r] + bv1;
      a0[r] = v0;
      a1[r] = v1;
      p1[r] = v0 + v1;
      p2[r] = v0 * v0 + v1 * v1;
    }
#pragma unroll
    for (int m = 1; m <= 8; m <<= 1)
#pragma unroll
      for (int r = 0; r < 4; ++r) {
        p1[r] += __shfl_xor(p1[r], m);
        p2[r] += __shfl_xor(p2[r], m);
      }
    if (c16 == 0) {
#pragma unroll
      for (int r = 0; r < 4; ++r) {
        lnred[q * 4 + r][2 * w] = p1[r];
        lnred[q * 4 + r][2 * w + 1] = p2[r];
      }
    }
    bar_lds();
    float meanv = 0.f, rstdv = 0.f;
    if (lane < 16) {
      float S1 = 0.f, S2 = 0.f;
#pragma unroll
      for (int i = 0; i < 8; ++i) {
        S1 += lnred[lane][2 * i];
        S2 += lnred[lane][2 * i + 1];
      }
      meanv = S1 * (1.f / HH);
      float var = fmaxf(S2 * (1.f / HH) - meanv * meanv, 0.f);
      rstdv = rsqrtf(var + 1e-5f);
    }
#pragma unroll
    for (int r = 0; r < 4; ++r) {
      int row = q * 4 + r;
      float mean = __shfl(meanv, row);
      float rstd = __shfl(rstdv, row);
      float v0 = (a0[r] - mean) * rstd * gv0 + ev0;
      float v1 = (a1[r] - mean) * rstd * gv1 + ev1;
      dst[row][n0] = f2b(fmaxf(v0, 0.f));
      dst[row][n1] = f2b(fmaxf(v1, 0.f));
    }
    bar_lds();
  };

  loadW1(0);
  loadP(0);
  float costreg = 0.f;

#pragma unroll 1
  for (int t = 0; t < NSTEP; ++t) {
    const float b1v0 = b1[t * HH + n0], b1v1 = b1[t * HH + n1];
    const float g1v0 = g1[t * HH + n0], g1v1 = g1[t * HH + n1];
    const float e1v0 = be1[t * HH + n0], e1v1 = be1[t * HH + n1];
    const float b2v0 = b2[t * HH + n0], b2v1 = b2[t * HH + n1];
    const float g2v0 = g2[t * HH + n0], g2v1 = g2[t * HH + n1];
    const float e2v0 = be2[t * HH + n0], e2v1 = be2[t * HH + n1];
    const float bov = cvalid ? bo[t * SS + col] : 0.f;

    // ===== GEMM1: h1[16x256] = s @ W1[t].T =====
    f32x4 acc0 = (f32x4){0.f, 0.f, 0.f, 0.f};
    f32x4 acc1 = (f32x4){0.f, 0.f, 0.f, 0.f};
#pragma unroll
    for (int ks = 0; ks < 4; ++ks) {
      bf16x8 a = *(const bf16x8*)&sbuf[c16][ks * 32 + q * 8];
      acc0 = MFMA(a, w1f[2 * ks + 0], acc0);
      acc1 = MFMA(a, w1f[2 * ks + 1], acc1);
    }

    // prefetch W2[t] (pinned: issues NOW, retires under LN1/barriers)
    bf16x8 w2f[16];
#pragma unroll
    for (int ks = 0; ks < 8; ++ks) {
      if (MODE == 0) {
        w2f[2 * ks + 0] = *(const bf16x8*)&W2g[W2G_OFF(t, 2 * w, ks) + lane * 8];
        w2f[2 * ks + 1] = *(const bf16x8*)&W2g[W2G_OFF(t, 2 * w + 1, ks) + lane * 8];
      } else {
        const int k = ks * 32 + q * 8;
        w2f[2 * ks + 0] = cvt8(W2f + ((size_t)t * HH + n0) * HH + k);
        w2f[2 * ks + 1] = cvt8(W2f + ((size_t)t * HH + n1) * HH + k);
      }
    }
    pin_loads();

    ln_epi(acc0, acc1, b1v0, b1v1, g1v0, g1v1, e1v0, e1v1, xb1);

    // ===== GEMM2: h2[16x256] = x1 @ W2[t].T (split acc chains) =====
    f32x4 acc0b = (f32x4){0.f, 0.f, 0.f, 0.f};
    f32x4 acc1b = (f32x4){0.f, 0.f, 0.f, 0.f};
    acc0 = (f32x4){0.f, 0.f, 0.f, 0.f};
    acc1 = (f32x4){0.f, 0.f, 0.f, 0.f};
#pragma unroll
    for (int ks = 0; ks < 4; ++ks) {
      bf16x8 a = *(const bf16x8*)&xb1[c16][ks * 32 + q * 8];
      acc0 = MFMA(a, w2f[2 * ks + 0], acc0);
      acc1 = MFMA(a, w2f[2 * ks + 1], acc1);
    }
#pragma unroll
    for (int ks = 4; ks < 8; ++ks) {
      bf16x8 a = *(const bf16x8*)&xb1[c16][ks * 32 + q * 8];
      acc0b = MFMA(a, w2f[2 * ks + 0], acc0b);
      acc1b = MFMA(a, w2f[2 * ks + 1], acc1b);
    }
    acc0 = acc0 + acc0b;
    acc1 = acc1 + acc1b;

    // prefetch Wo[t] (pinned)
    bf16x8 wof[8];
#pragma unroll
    for (int ks = 0; ks < 8; ++ks) {
      if (MODE == 0) {
        wof[ks] = *(const bf16x8*)&Wog[WOG_OFF(t, w, ks) + lane * 8];
      } else {
        const int k = ks * 32 + q * 8;
        if (cvalid) {
          wof[ks] = cvt8(Wof + ((size_t)t * SS + col) * HH + k);
        } else {
          bf16x8 z = {0, 0, 0, 0, 0, 0, 0, 0};
          wof[ks] = z;
        }
      }
    }
    pin_loads();

    ln_epi(acc0, acc1, b2v0, b2v1, g2v0, g2v1, e2v0, e2v1, xb2);

    // ===== GEMM3: o[16x(100p128)] = x2 @ Wo[t].T (split acc chains) =====
    f32x4 a3 = (f32x4){0.f, 0.f, 0.f, 0.f};
    f32x4 a3b = (f32x4){0.f, 0.f, 0.f, 0.f};
#pragma unroll
    for (int ks = 0; ks < 4; ++ks) {
      bf16x8 a = *(const bf16x8*)&xb2[c16][ks * 32 + q * 8];
      a3 = MFMA(a, wof[ks], a3);
    }
#pragma unroll
    for (int ks = 4; ks < 8; ++ks) {
      bf16x8 a = *(const bf16x8*)&xb2[c16][ks * 32 + q * 8];
      a3b = MFMA(a, wof[ks], a3b);
    }
    a3 = a3 + a3b;

    // prefetch W1[t+1] + prices[t+1] (pinned; retires under epilogue+barrier)
    float pcur[4];
#pragma unroll
    for (int r = 0; r < 4; ++r) pcur[r] = pr[r];
    const int tn = (t + 1 < NSTEP) ? t + 1 : 0;
    loadW1(tn);
    loadP(t + 1);
    pin_loads();

    // ===== epilogue =====
#pragma unroll
    for (int r = 0; r < 4; ++r) {
      float o = a3[r] + bov;
      float a = fminf(o, s_reg[r]);
      float pa = pcur[r] * a;
      costreg += pa + 0.01f * pa * pa;
      s_reg[r] -= a;
      if (cvalid) sbuf[q * 4 + r][col] = f2b(s_reg[r]);
    }
    bar_lds();
  }

  // ===== terminal =====
#pragma unroll
  for (int r = 0; r < 4; ++r) {
    float pa = pr[r] * s_reg[r];
    costreg += pa + 0.01f * pa * pa;
  }

#pragma unroll
  for (int m = 1; m < 64; m <<= 1) costreg += __shfl_xor(costreg, m);
  if (lane == 0) wsum[w] = costreg;
  __syncthreads();
  if (tid == 0) {
    float tot = 0.f;
#pragma unroll
    for (int i = 0; i < 8; ++i) tot += wsum[i];
    atomicAdd(out, tot * (1.f / NBATCH));
  }
}

extern "C" void kernel_launch(void* const* d_in, const int* in_sizes, int n_in,
                              void* d_out, int out_size, void* d_ws, size_t ws_size,
                              hipStream_t stream) {
  const float* s0 = (const float*)d_in[0];
  const float* prices = (const float*)d_in[1];
  const float* W1 = (const float*)d_in[2];
  const float* b1 = (const float*)d_in[3];
  const float* g1 = (const float*)d_in[4];
  const float* be1 = (const float*)d_in[5];
  const float* W2 = (const float*)d_in[6];
  const float* b2 = (const float*)d_in[7];
  const float* g2 = (const float*)d_in[8];
  const float* be2 = (const float*)d_in[9];
  const float* Wo = (const float*)d_in[10];
  const float* bo = (const float*)d_in[11];
  float* out = (float*)d_out;

  const size_t need = (N_W1G + N_W2G + N_WOG) * sizeof(short);

  if (ws_size >= need) {
    short* W1g = (short*)d_ws;
    short* W2g = W1g + N_W1G;
    short* Wog = W2g + N_W2G;
    prep<<<dim3(2000), dim3(256), 0, stream>>>(W1, b1, W2, Wo, W1g, W2g, Wog, out);
    run_kernel<0><<<dim3(NBLK), dim3(NTHR), 0, stream>>>(
        s0, prices, b1, g1, be1, b2, g2, be2, bo,
        W1, W2, Wo, W1g, W2g, Wog, out);
  } else {
    zero_out<<<dim3(1), dim3(64), 0, stream>>>(out);
    run_kernel<1><<<dim3(NBLK), dim3(NTHR), 0, stream>>>(
        s0, prices, b1, g1, be1, b2, g2, be2, bo,
        W1, W2, Wo, (const short*)nullptr, (const short*)nullptr, (const short*)nullptr, out);
  }
}